// Round 2
// baseline (417.744 us; speedup 1.0000x reference)
//
#include <hip/hip_runtime.h>

// StatefulRecurrent: s_t = A*s_{t-1} + x_t (complex diagonal A), out = [Re(s),Im(s)].
// B=16, T=4096, D=512. Two-kernel chunked scan.
//
// This revision: 16 B/lane everywhere (4 consecutive d per thread).
//   - x loads: float2 (8 B/lane) -> float4 (16 B/lane); wave reads 1 KB/step.
//   - out stores: 2x float4 per step (32 B/lane); wave writes 2 KB/step; store
//     instruction count halved chip-wide.
//   - buf: 2x float4 per thread.
//   - K2 x loads back to NORMAL (L3-resident from K1; nt-load semantics unproven).
//     out stores stay NONTEMPORAL (proven -19us: stops the 268 MB stream from
//     evicting x from L3 / buf from L2).
// Grid: 512 blocks x 256 threads. Block n: sp = n&31 (seg-pair), b = n>>5.
//   Wave g: seg = sp*2 + (g>>1), dh = g&1, d = dh*256 + lane*4.

#define B_  16
#define T_  4096
#define D_  512
#define SEG 64
#define NS  (T_ / SEG)     // 64 segments
#define BD  (B_ * D_)      // 8192 float2 entries per segment in buf

typedef float v4f __attribute__((ext_vector_type(4)));

__global__ __launch_bounds__(256) void seg_agg_kernel(
    const float* __restrict__ x,
    const float* __restrict__ Ar_g, const float* __restrict__ Ai_g,
    float2* __restrict__ buf) {
  int tid  = threadIdx.x;
  int lane = tid & 63;
  int g    = tid >> 6;
  int n    = blockIdx.x;
  int sp   = n & 31;
  int b    = n >> 5;
  int seg  = sp * 2 + (g >> 1);
  int dh   = g & 1;
  int d    = dh * 256 + lane * 4;
  int t0   = seg * SEG;

  float4 Ar = *(const float4*)(Ar_g + d);
  float4 Ai = *(const float4*)(Ai_g + d);
  float s0r = 0.f, s0i = 0.f, s1r = 0.f, s1i = 0.f;
  float s2r = 0.f, s2i = 0.f, s3r = 0.f, s3i = 0.f;
  // NORMAL (caching) loads on purpose: this pass populates L3 with x for apply_kernel.
  const float4* xp = (const float4*)(x + ((size_t)(b * T_ + t0)) * D_ + d);
#pragma unroll 8
  for (int k = 0; k < SEG; ++k) {
    float4 xv = xp[(size_t)k * (D_ / 4)];
    float n0r = fmaf(s0r, Ar.x, fmaf(-s0i, Ai.x, xv.x));
    float n0i = fmaf(s0r, Ai.x, s0i * Ar.x);
    float n1r = fmaf(s1r, Ar.y, fmaf(-s1i, Ai.y, xv.y));
    float n1i = fmaf(s1r, Ai.y, s1i * Ar.y);
    float n2r = fmaf(s2r, Ar.z, fmaf(-s2i, Ai.z, xv.z));
    float n2i = fmaf(s2r, Ai.z, s2i * Ar.z);
    float n3r = fmaf(s3r, Ar.w, fmaf(-s3i, Ai.w, xv.w));
    float n3i = fmaf(s3r, Ai.w, s3i * Ar.w);
    s0r = n0r; s0i = n0i; s1r = n1r; s1i = n1i;
    s2r = n2r; s2i = n2i; s3r = n3r; s3i = n3i;
  }
  // buf element index (float2 units): seg*BD + b*D_ + d ; 4 float2 = 2 float4, 32B aligned.
  float* bp = (float*)(buf + (size_t)seg * BD + b * D_ + d);
  *(float4*)(bp + 0) = make_float4(s0r, s0i, s1r, s1i);
  *(float4*)(bp + 4) = make_float4(s2r, s2i, s3r, s3i);
}

__global__ __launch_bounds__(256) void apply_kernel(
    const float* __restrict__ x,
    const float* __restrict__ Ar_g, const float* __restrict__ Ai_g,
    const float2* __restrict__ buf,
    float4* __restrict__ out4) {
  int tid  = threadIdx.x;
  int lane = tid & 63;
  int g    = tid >> 6;
  int n    = blockIdx.x;
  int sp   = n & 31;
  int b    = n >> 5;
  int seg  = sp * 2 + (g >> 1);
  int dh   = g & 1;
  int d    = dh * 256 + lane * 4;
  int t0   = seg * SEG;

  float4 Ar = *(const float4*)(Ar_g + d);
  float4 Ai = *(const float4*)(Ai_g + d);

  // A^64 per d-component by 6 squarings
  float p0r = Ar.x, p0i = Ai.x, p1r = Ar.y, p1i = Ai.y;
  float p2r = Ar.z, p2i = Ai.z, p3r = Ar.w, p3i = Ai.w;
#pragma unroll
  for (int q = 0; q < 6; ++q) {
    float t0r = p0r * p0r - p0i * p0i; float t0i = 2.f * p0r * p0i;
    float t1r = p1r * p1r - p1i * p1i; float t1i = 2.f * p1r * p1i;
    float t2r = p2r * p2r - p2i * p2i; float t2i = 2.f * p2r * p2i;
    float t3r = p3r * p3r - p3i * p3i; float t3i = 2.f * p3r * p3i;
    p0r = t0r; p0i = t0i; p1r = t1r; p1i = t1i;
    p2r = t2r; p2i = t2i; p3r = t3r; p3i = t3i;
  }

  // Incoming state: S = sum_{j<seg} A^{64(seg-1-j)} * agg_j, via S = A64*S + agg_j.
  // buf is 4 MB, L2/L3 resident (nt out-stream doesn't evict it). Unroll 8.
  float S0r = 0.f, S0i = 0.f, S1r = 0.f, S1i = 0.f;
  float S2r = 0.f, S2i = 0.f, S3r = 0.f, S3i = 0.f;
  const float* bbase = (const float*)(buf + b * D_ + d);
#pragma unroll 8
  for (int j = 0; j < seg; ++j) {
    float4 g0 = *(const float4*)(bbase + (size_t)j * (BD * 2) + 0);
    float4 g1 = *(const float4*)(bbase + (size_t)j * (BD * 2) + 4);
    float n0r = fmaf(p0r, S0r, fmaf(-p0i, S0i, g0.x));
    float n0i = fmaf(p0i, S0r, fmaf(p0r, S0i, g0.y));
    float n1r = fmaf(p1r, S1r, fmaf(-p1i, S1i, g0.z));
    float n1i = fmaf(p1i, S1r, fmaf(p1r, S1i, g0.w));
    float n2r = fmaf(p2r, S2r, fmaf(-p2i, S2i, g1.x));
    float n2i = fmaf(p2i, S2r, fmaf(p2r, S2i, g1.y));
    float n3r = fmaf(p3r, S3r, fmaf(-p3i, S3i, g1.z));
    float n3i = fmaf(p3i, S3r, fmaf(p3r, S3i, g1.w));
    S0r = n0r; S0i = n0i; S1r = n1r; S1i = n1i;
    S2r = n2r; S2i = n2i; S3r = n3r; S3i = n3i;
  }

  // Replay segment from incoming state. x: normal loads (L3 hit from K1's warm).
  // out: nontemporal stores (never read again; don't thrash L2/L3).
  const float4* xp = (const float4*)(x + ((size_t)(b * T_ + t0)) * D_ + d);
  v4f* op = (v4f*)(out4 + (((size_t)(b * T_ + t0)) * D_ + d) / 2);
#pragma unroll 8
  for (int k = 0; k < SEG; ++k) {
    float4 xv = xp[(size_t)k * (D_ / 4)];
    float n0r = fmaf(S0r, Ar.x, fmaf(-S0i, Ai.x, xv.x));
    float n0i = fmaf(S0r, Ai.x, S0i * Ar.x);
    float n1r = fmaf(S1r, Ar.y, fmaf(-S1i, Ai.y, xv.y));
    float n1i = fmaf(S1r, Ai.y, S1i * Ar.y);
    float n2r = fmaf(S2r, Ar.z, fmaf(-S2i, Ai.z, xv.z));
    float n2i = fmaf(S2r, Ai.z, S2i * Ar.z);
    float n3r = fmaf(S3r, Ar.w, fmaf(-S3i, Ai.w, xv.w));
    float n3i = fmaf(S3r, Ai.w, S3i * Ar.w);
    S0r = n0r; S0i = n0i; S1r = n1r; S1i = n1i;
    S2r = n2r; S2i = n2i; S3r = n3r; S3i = n3i;
    v4f o0 = {S0r, S0i, S1r, S1i};
    v4f o1 = {S2r, S2i, S3r, S3i};
    __builtin_nontemporal_store(o0, op + (size_t)k * (D_ / 2) + 0);
    __builtin_nontemporal_store(o1, op + (size_t)k * (D_ / 2) + 1);
  }
}

extern "C" void kernel_launch(void* const* d_in, const int* in_sizes, int n_in,
                              void* d_out, int out_size, void* d_ws, size_t ws_size,
                              hipStream_t stream) {
  const float* x  = (const float*)d_in[0];
  const float* Ar = (const float*)d_in[1];
  const float* Ai = (const float*)d_in[2];
  float4* out = (float4*)d_out;
  float2* buf = (float2*)d_ws;  // NS*BD float2 = 4 MB scratch

  seg_agg_kernel<<<dim3(512), dim3(256), 0, stream>>>(x, Ar, Ai, buf);
  apply_kernel<<<dim3(512), dim3(256), 0, stream>>>(x, Ar, Ai, buf, out);
}

// Round 3
// 370.941 us; speedup vs baseline: 1.1262x; 1.1262x over previous
//
#include <hip/hip_runtime.h>

// StatefulRecurrent: s_t = A*s_{t-1} + x_t (complex diagonal A), out = [Re(s),Im(s)].
// B=16, T=4096, D=512. SINGLE fused kernel, block-local chunked scan:
//   - Block owns (b, 32-d slice) x all T. 1024 threads = 64 segments x 16 d-pairs.
//   - Phase 1: each thread scans its 64-step segment (zero-init), x kept in
//     REGISTERS (128 VGPR, fully unrolled static indexing), aggregate -> LDS.
//   - __syncthreads (the only barrier; scan dependency is intra-block).
//   - Phase 2: incoming state by serial rescan of LDS aggregates (S = A^64*S + agg_j).
//   - Phase 3: replay from registers, nt-store float4 per step.
// HBM traffic = exactly 134 MB x-read (once, nt) + 268 MB out-write (nt) ~ 64 us floor.
// No workspace, no second kernel, no inter-kernel drain, no buf stream.
// LDS agg[64][16] float4: rescan reads 16x16B/iter = 2-way bank alias + broadcast -> free.

#define B_  16
#define T_  4096
#define D_  512
#define SEG 64
#define NS  (T_ / SEG)   // 64 segments
#define NDP 16           // d-pairs per block (32 consecutive d)

typedef float v2f __attribute__((ext_vector_type(2)));
typedef float v4f __attribute__((ext_vector_type(4)));

__global__ __launch_bounds__(1024, 4) void fused_scan_kernel(
    const float* __restrict__ x,
    const float* __restrict__ Ar_g, const float* __restrict__ Ai_g,
    v4f* __restrict__ out4) {
  int tid  = threadIdx.x;
  int dp   = tid & (NDP - 1);   // d-pair within block: lanes 0..15 contiguous d
  int seg  = tid >> 4;          // 0..63
  int n    = blockIdx.x;
  int dblk = n & 15;
  int b    = n >> 4;
  int d    = dblk * (2 * NDP) + dp * 2;
  int t0   = seg * SEG;

  __shared__ v4f agg[NS][NDP];  // 16 KB

  float2 Ar = *(const float2*)(Ar_g + d);
  float2 Ai = *(const float2*)(Ai_g + d);

  // ---- Phase 1: local zero-init scan; x -> registers (static indices only) ----
  const v2f* xp = (const v2f*)(x + ((size_t)(b * T_ + t0)) * D_ + d);
  float xa[SEG], xb[SEG];
  float s0r = 0.f, s0i = 0.f, s1r = 0.f, s1i = 0.f;
#pragma unroll
  for (int k = 0; k < SEG; ++k) {
    v2f xv = __builtin_nontemporal_load(xp + (size_t)k * (D_ / 2));  // single use of x
    xa[k] = xv.x; xb[k] = xv.y;
    float n0r = fmaf(s0r, Ar.x, fmaf(-s0i, Ai.x, xv.x));
    float n0i = fmaf(s0r, Ai.x, s0i * Ar.x);
    float n1r = fmaf(s1r, Ar.y, fmaf(-s1i, Ai.y, xv.y));
    float n1i = fmaf(s1r, Ai.y, s1i * Ar.y);
    s0r = n0r; s0i = n0i; s1r = n1r; s1i = n1i;
  }
  agg[seg][dp] = (v4f){s0r, s0i, s1r, s1i};
  __syncthreads();

  // ---- A^64 per d-component by 6 squarings ----
  float p0r = Ar.x, p0i = Ai.x, p1r = Ar.y, p1i = Ai.y;
#pragma unroll
  for (int q = 0; q < 6; ++q) {
    float t0r = p0r * p0r - p0i * p0i; float t0i = 2.f * p0r * p0i;
    float t1r = p1r * p1r - p1i * p1i; float t1i = 2.f * p1r * p1i;
    p0r = t0r; p0i = t0i; p1r = t1r; p1i = t1i;
  }

  // ---- Phase 2: incoming state S = sum_{j<seg} A^{64(seg-1-j)} agg_j (LDS rescan) ----
  // Trip count varies by <=3 within a wave (segs 4w..4w+3) -> negligible divergence.
  float S0r = 0.f, S0i = 0.f, S1r = 0.f, S1i = 0.f;
  for (int j = 0; j < seg; ++j) {
    v4f g = agg[j][dp];
    float n0r = fmaf(p0r, S0r, fmaf(-p0i, S0i, g.x));
    float n0i = fmaf(p0i, S0r, fmaf(p0r, S0i, g.y));
    float n1r = fmaf(p1r, S1r, fmaf(-p1i, S1i, g.z));
    float n1i = fmaf(p1i, S1r, fmaf(p1r, S1i, g.w));
    S0r = n0r; S0i = n0i; S1r = n1r; S1i = n1i;
  }

  // ---- Phase 3: replay from registers, nt-store [Re,Im] pairs (float4/step) ----
  // out4 index: ((b*T+t)*D + d)*2 floats / 4 = (b*T+t)*(D/2) + d/2
  v4f* op = out4 + ((size_t)(b * T_ + t0)) * (D_ / 2) + (d >> 1);
#pragma unroll
  for (int k = 0; k < SEG; ++k) {
    float n0r = fmaf(S0r, Ar.x, fmaf(-S0i, Ai.x, xa[k]));
    float n0i = fmaf(S0r, Ai.x, S0i * Ar.x);
    float n1r = fmaf(S1r, Ar.y, fmaf(-S1i, Ai.y, xb[k]));
    float n1i = fmaf(S1r, Ai.y, S1i * Ar.y);
    S0r = n0r; S0i = n0i; S1r = n1r; S1i = n1i;
    v4f ov = {S0r, S0i, S1r, S1i};
    __builtin_nontemporal_store(ov, op + (size_t)k * (D_ / 2));
  }
}

extern "C" void kernel_launch(void* const* d_in, const int* in_sizes, int n_in,
                              void* d_out, int out_size, void* d_ws, size_t ws_size,
                              hipStream_t stream) {
  const float* x  = (const float*)d_in[0];
  const float* Ar = (const float*)d_in[1];
  const float* Ai = (const float*)d_in[2];
  v4f* out = (v4f*)d_out;

  // 16 b x 16 d-blocks = 256 blocks x 1024 threads (16 waves/CU, ~4 waves/SIMD)
  fused_scan_kernel<<<dim3(256), dim3(1024), 0, stream>>>(x, Ar, Ai, out);
}